// Round 1
// baseline (1121.414 us; speedup 1.0000x reference)
//
#include <hip/hip_runtime.h>

#define TOKENS 8192
#define KDIM   4096
#define OUTF   11008

typedef int int4v __attribute__((ext_vector_type(4)));

// ---------------- kernel 1: per-token dynamic asymmetric int8 quant ----------------
// one block per token row; 256 threads x 16 floats = 4096
__global__ __launch_bounds__(256) void quant_x_kernel(
    const float* __restrict__ x, char* __restrict__ q8,
    float* __restrict__ sc, float* __restrict__ zpv, int* __restrict__ qsum)
{
    const int t = blockIdx.x;
    const int tid = threadIdx.x;
    const float4* xr = (const float4*)(x + (size_t)t * KDIM);

    float4 v[4];
    float mn = 3.0e38f, mx = -3.0e38f;
#pragma unroll
    for (int j = 0; j < 4; ++j) {
        v[j] = xr[tid + 256 * j];
        mn = fminf(mn, fminf(fminf(v[j].x, v[j].y), fminf(v[j].z, v[j].w)));
        mx = fmaxf(mx, fmaxf(fmaxf(v[j].x, v[j].y), fmaxf(v[j].z, v[j].w)));
    }
#pragma unroll
    for (int off = 32; off > 0; off >>= 1) {
        mn = fminf(mn, __shfl_down(mn, off, 64));
        mx = fmaxf(mx, __shfl_down(mx, off, 64));
    }
    __shared__ float smn[4], smx[4];
    __shared__ int ssum[4];
    if ((tid & 63) == 0) { smn[tid >> 6] = mn; smx[tid >> 6] = mx; }
    __syncthreads();
    mn = fminf(fminf(smn[0], smn[1]), fminf(smn[2], smn[3]));
    mx = fmaxf(fmaxf(smx[0], smx[1]), fmaxf(smx[2], smx[3]));

    // torchao choose_qparams_per_token_asymmetric, QMIN=-128 QMAX=127
    const float min_neg = fminf(mn, 0.0f);
    const float max_pos = fmaxf(mx, 0.0f);
    float scale = (max_pos - min_neg) / 255.0f;
    scale = fmaxf(scale, 1.1920928955078125e-07f);  // FLT_EPSILON
    const float dmin = min_neg / scale;
    const float dmax = max_pos / scale;
    float zpf = ((-128.0f + dmin) + (127.0f + dmax) > 0.0f) ? (-128.0f - dmin)
                                                            : (127.0f - dmax);
    zpf = fminf(fmaxf(rintf(zpf), -128.0f), 127.0f);  // rintf = round-half-even
    const float inv = 1.0f / scale;

    int s = 0;
    int* qrow = (int*)(q8 + (size_t)t * KDIM);
#pragma unroll
    for (int j = 0; j < 4; ++j) {
        int q0 = (int)fminf(fmaxf(rintf(v[j].x * inv) + zpf, -128.0f), 127.0f);
        int q1 = (int)fminf(fmaxf(rintf(v[j].y * inv) + zpf, -128.0f), 127.0f);
        int q2 = (int)fminf(fmaxf(rintf(v[j].z * inv) + zpf, -128.0f), 127.0f);
        int q3 = (int)fminf(fmaxf(rintf(v[j].w * inv) + zpf, -128.0f), 127.0f);
        s += q0 + q1 + q2 + q3;
        qrow[tid + 256 * j] = (q0 & 255) | ((q1 & 255) << 8) | ((q2 & 255) << 16) | (q3 << 24);
    }
#pragma unroll
    for (int off = 32; off > 0; off >>= 1) s += __shfl_down(s, off, 64);
    if ((tid & 63) == 0) ssum[tid >> 6] = s;
    __syncthreads();
    if (tid == 0) {
        sc[t] = scale;
        zpv[t] = zpf;
        qsum[t] = ssum[0] + ssum[1] + ssum[2] + ssum[3];
    }
}

// ---------------- kernel 2: repack int32 weight -> int8 + row sums ----------------
__global__ __launch_bounds__(256) void pack_w_kernel(
    const int* __restrict__ w, char* __restrict__ w8, int* __restrict__ wsum)
{
    const int o = blockIdx.x;
    const int tid = threadIdx.x;
    const int4* wr = (const int4*)(w + (size_t)o * KDIM);
    int* dst = (int*)(w8 + (size_t)o * KDIM);
    int s = 0;
#pragma unroll
    for (int j = 0; j < 4; ++j) {
        int4 a = wr[tid + 256 * j];
        s += a.x + a.y + a.z + a.w;
        dst[tid + 256 * j] = (a.x & 255) | ((a.y & 255) << 8) | ((a.z & 255) << 16) | (a.w << 24);
    }
#pragma unroll
    for (int off = 32; off > 0; off >>= 1) s += __shfl_down(s, off, 64);
    __shared__ int ss[4];
    if ((tid & 63) == 0) ss[tid >> 6] = s;
    __syncthreads();
    if (tid == 0) wsum[o] = ss[0] + ss[1] + ss[2] + ss[3];
}

// ---------------- kernel 3: int8 GEMM (m97 structure), 128x128 tile, BK=128B ----------------
__device__ __forceinline__ void async_cp16(const void* g, void* l) {
    __builtin_amdgcn_global_load_lds(
        (const __attribute__((address_space(1))) void*)g,
        (__attribute__((address_space(3))) void*)l, 16, 0, 0);
}

__global__ __launch_bounds__(256) void gemm_i8_kernel(
    const char* __restrict__ q8, const char* __restrict__ w8,
    const float* __restrict__ sc, const float* __restrict__ zpv,
    const int* __restrict__ qsum,
    const float* __restrict__ scales, const float* __restrict__ zeros,
    const int* __restrict__ wsum, float* __restrict__ out)
{
    const int tid = threadIdx.x;
    const int wave = tid >> 6;
    const int lane = tid & 63;
    const int o0 = blockIdx.x * 128;  // N tile (86)
    const int t0 = blockIdx.y * 128;  // M tile (64)

    __shared__ char smem[128 * 128 * 2];  // 32 KB: sA then sB, rows of 128 B
    char* sA = smem;
    char* sB = smem + 128 * 128;

    const char* Ag = q8 + (size_t)t0 * KDIM;
    const char* Bg = w8 + (size_t)o0 * KDIM;

    const int wm = (wave & 1) * 64;
    const int wn = (wave >> 1) * 64;
    const int lr = lane & 15;
    const int kb = (lane >> 4) * 16;  // 16B k-chunk within 64B MFMA K-slice

    int4v acc[4][4];
#pragma unroll
    for (int mi = 0; mi < 4; ++mi)
#pragma unroll
        for (int ni = 0; ni < 4; ++ni)
            acc[mi][ni] = (int4v){0, 0, 0, 0};

    for (int k0 = 0; k0 < KDIM; k0 += 128) {
        // stage A tile (128 rows x 128 B) and B tile: 4+4 iterations of 256 lanes x 16B
#pragma unroll
        for (int it = 0; it < 4; ++it) {
            const int idx = it * 256 + tid;
            const int r = idx >> 3;
            const int c = (idx & 7) << 4;
            async_cp16(Ag + (size_t)r * KDIM + k0 + c, sA + idx * 16);
        }
#pragma unroll
        for (int it = 0; it < 4; ++it) {
            const int idx = it * 256 + tid;
            const int r = idx >> 3;
            const int c = (idx & 7) << 4;
            async_cp16(Bg + (size_t)r * KDIM + k0 + c, sB + idx * 16);
        }
        __builtin_amdgcn_s_waitcnt(0);
        __syncthreads();

#pragma unroll
        for (int kk = 0; kk < 128; kk += 64) {
            int4v a[4], b[4];
#pragma unroll
            for (int mi = 0; mi < 4; ++mi)
                a[mi] = *(const int4v*)(sA + (wm + mi * 16 + lr) * 128 + kk + kb);
#pragma unroll
            for (int ni = 0; ni < 4; ++ni)
                b[ni] = *(const int4v*)(sB + (wn + ni * 16 + lr) * 128 + kk + kb);
#pragma unroll
            for (int mi = 0; mi < 4; ++mi)
#pragma unroll
                for (int ni = 0; ni < 4; ++ni)
                    acc[mi][ni] = __builtin_amdgcn_mfma_i32_16x16x64_i8(
                        a[mi], b[ni], acc[mi][ni], 0, 0, 0);
        }
        __syncthreads();
    }

    // epilogue: out[t,o] = st*so*( dot - zp_t*Wsum_o - z_o*(Qsum_t - 4096*zp_t) )
#pragma unroll
    for (int mi = 0; mi < 4; ++mi) {
        const int tb = t0 + wm + mi * 16 + ((lane >> 4) << 2);
        float st4[4], zp4[4], qs4[4];
        int zi4[4];
#pragma unroll
        for (int r = 0; r < 4; ++r) {
            st4[r] = sc[tb + r];
            zp4[r] = zpv[tb + r];
            zi4[r] = (int)zp4[r];
            qs4[r] = (float)qsum[tb + r];
        }
#pragma unroll
        for (int ni = 0; ni < 4; ++ni) {
            const int o = o0 + wn + ni * 16 + lr;
            const float so = scales[o];
            const float zo = zeros[o];
            const long long wso = (long long)wsum[o];
#pragma unroll
            for (int r = 0; r < 4; ++r) {
                long long iv = (long long)acc[mi][ni][r] - (long long)zi4[r] * wso;
                float val = (float)iv - zo * (qs4[r] - 4096.0f * zp4[r]);
                out[(size_t)(tb + r) * OUTF + o] = st4[r] * so * val;
            }
        }
    }
}

// ---------------- launch ----------------
extern "C" void kernel_launch(void* const* d_in, const int* in_sizes, int n_in,
                              void* d_out, int out_size, void* d_ws, size_t ws_size,
                              hipStream_t stream) {
    const float* x      = (const float*)d_in[0];
    const int*   w      = (const int*)d_in[1];   // int8 values stored as int32
    const float* scales = (const float*)d_in[2];
    const float* zeros  = (const float*)d_in[3];
    float* out = (float*)d_out;

    char* ws = (char*)d_ws;
    char*  q8   = ws;                              // 8192*4096      = 33554432 B
    char*  w8   = ws + 33554432;                   // 11008*4096     = 45088768 B
    float* sc   = (float*)(ws + 78643200);         // 8192*4
    float* zp   = (float*)(ws + 78675968);         // 8192*4
    int*   qsum = (int*)(ws + 78708736);           // 8192*4
    int*   wsum = (int*)(ws + 78741504);           // 11008*4

    quant_x_kernel<<<TOKENS, 256, 0, stream>>>(x, q8, sc, zp, qsum);
    pack_w_kernel<<<OUTF, 256, 0, stream>>>(w, w8, wsum);
    dim3 grid(OUTF / 128, TOKENS / 128);  // (86, 64)
    gemm_i8_kernel<<<grid, 256, 0, stream>>>(q8, w8, sc, zp, qsum, scales, zeros, wsum, out);
}

// Round 2
// 1088.351 us; speedup vs baseline: 1.0304x; 1.0304x over previous
//
#include <hip/hip_runtime.h>

#define TOKENS 8192
#define KDIM   4096
#define OUTF   11008

typedef int int4v __attribute__((ext_vector_type(4)));

// ---------------- kernel 1: per-token dynamic asymmetric int8 quant ----------------
__global__ __launch_bounds__(256) void quant_x_kernel(
    const float* __restrict__ x, char* __restrict__ q8,
    float* __restrict__ sc, float* __restrict__ zpv, int* __restrict__ qsum)
{
    const int t = blockIdx.x;
    const int tid = threadIdx.x;
    const float4* xr = (const float4*)(x + (size_t)t * KDIM);

    float4 v[4];
    float mn = 3.0e38f, mx = -3.0e38f;
#pragma unroll
    for (int j = 0; j < 4; ++j) {
        v[j] = xr[tid + 256 * j];
        mn = fminf(mn, fminf(fminf(v[j].x, v[j].y), fminf(v[j].z, v[j].w)));
        mx = fmaxf(mx, fmaxf(fmaxf(v[j].x, v[j].y), fmaxf(v[j].z, v[j].w)));
    }
#pragma unroll
    for (int off = 32; off > 0; off >>= 1) {
        mn = fminf(mn, __shfl_down(mn, off, 64));
        mx = fmaxf(mx, __shfl_down(mx, off, 64));
    }
    __shared__ float smn[4], smx[4];
    __shared__ int ssum[4];
    if ((tid & 63) == 0) { smn[tid >> 6] = mn; smx[tid >> 6] = mx; }
    __syncthreads();
    mn = fminf(fminf(smn[0], smn[1]), fminf(smn[2], smn[3]));
    mx = fmaxf(fmaxf(smx[0], smx[1]), fmaxf(smx[2], smx[3]));

    const float min_neg = fminf(mn, 0.0f);
    const float max_pos = fmaxf(mx, 0.0f);
    float scale = (max_pos - min_neg) / 255.0f;
    scale = fmaxf(scale, 1.1920928955078125e-07f);  // FLT_EPSILON
    const float dmin = min_neg / scale;
    const float dmax = max_pos / scale;
    float zpf = ((-128.0f + dmin) + (127.0f + dmax) > 0.0f) ? (-128.0f - dmin)
                                                            : (127.0f - dmax);
    zpf = fminf(fmaxf(rintf(zpf), -128.0f), 127.0f);  // round-half-even
    const float inv = 1.0f / scale;

    int s = 0;
    int* qrow = (int*)(q8 + (size_t)t * KDIM);
#pragma unroll
    for (int j = 0; j < 4; ++j) {
        int q0 = (int)fminf(fmaxf(rintf(v[j].x * inv) + zpf, -128.0f), 127.0f);
        int q1 = (int)fminf(fmaxf(rintf(v[j].y * inv) + zpf, -128.0f), 127.0f);
        int q2 = (int)fminf(fmaxf(rintf(v[j].z * inv) + zpf, -128.0f), 127.0f);
        int q3 = (int)fminf(fmaxf(rintf(v[j].w * inv) + zpf, -128.0f), 127.0f);
        s += q0 + q1 + q2 + q3;
        qrow[tid + 256 * j] = (q0 & 255) | ((q1 & 255) << 8) | ((q2 & 255) << 16) | (q3 << 24);
    }
#pragma unroll
    for (int off = 32; off > 0; off >>= 1) s += __shfl_down(s, off, 64);
    if ((tid & 63) == 0) ssum[tid >> 6] = s;
    __syncthreads();
    if (tid == 0) {
        sc[t] = scale;
        zpv[t] = zpf;
        qsum[t] = ssum[0] + ssum[1] + ssum[2] + ssum[3];
    }
}

// ---------------- kernel 2: repack int32 weight -> int8 + row sums ----------------
__global__ __launch_bounds__(256) void pack_w_kernel(
    const int* __restrict__ w, char* __restrict__ w8, int* __restrict__ wsum)
{
    const int o = blockIdx.x;
    const int tid = threadIdx.x;
    const int4* wr = (const int4*)(w + (size_t)o * KDIM);
    int* dst = (int*)(w8 + (size_t)o * KDIM);
    int s = 0;
#pragma unroll
    for (int j = 0; j < 4; ++j) {
        int4 a = wr[tid + 256 * j];
        s += a.x + a.y + a.z + a.w;
        dst[tid + 256 * j] = (a.x & 255) | ((a.y & 255) << 8) | ((a.z & 255) << 16) | (a.w << 24);
    }
#pragma unroll
    for (int off = 32; off > 0; off >>= 1) s += __shfl_down(s, off, 64);
    __shared__ int ss[4];
    if ((tid & 63) == 0) ss[tid >> 6] = s;
    __syncthreads();
    if (tid == 0) wsum[o] = ss[0] + ss[1] + ss[2] + ss[3];
}

// ---------------- kernel 3: int8 GEMM, 128x128 tile, BK=128B, XOR-swizzled LDS ----------------
// LDS layout: tile row r (128 B) holds 8 chunks of 16 B; slot c' within the row
// stores global k-chunk c = c' ^ (r & 7).  Staging keeps the linear
// wave-uniform-base + lane*16 LDS destination required by global_load_lds;
// only the per-lane GLOBAL source column is permuted (same 128 B segment, so
// coalescing is intact).  Read side: bank group = (c ^ swz)*4 with swz = lr&7,
// so each 16-lane phase spans all 32 banks (2-way aliasing only = free).
__device__ __forceinline__ void async_cp16(const void* g, void* l) {
    __builtin_amdgcn_global_load_lds(
        (const __attribute__((address_space(1))) void*)g,
        (__attribute__((address_space(3))) void*)l, 16, 0, 0);
}

__global__ __launch_bounds__(256) void gemm_i8_kernel(
    const char* __restrict__ q8, const char* __restrict__ w8,
    const float* __restrict__ sc, const float* __restrict__ zpv,
    const int* __restrict__ qsum,
    const float* __restrict__ scales, const float* __restrict__ zeros,
    const int* __restrict__ wsum, float* __restrict__ out)
{
    const int tid = threadIdx.x;
    const int wave = tid >> 6;
    const int lane = tid & 63;
    const int o0 = blockIdx.x * 128;  // N tile (86)
    const int t0 = blockIdx.y * 128;  // M tile (64)

    __shared__ char smem[128 * 128 * 2];  // 32 KB
    char* sA = smem;
    char* sB = smem + 128 * 128;

    const char* Ag = q8 + (size_t)t0 * KDIM;
    const char* Bg = w8 + (size_t)o0 * KDIM;

    const int wm = (wave & 1) * 64;
    const int wn = (wave >> 1) * 64;
    const int lr = lane & 15;
    const int kq = lane >> 4;   // which 16B chunk of the 64B MFMA K-slice
    const int swz = lr & 7;     // == (fragment row & 7) for all mi/ni

    int4v acc[4][4];
#pragma unroll
    for (int mi = 0; mi < 4; ++mi)
#pragma unroll
        for (int ni = 0; ni < 4; ++ni)
            acc[mi][ni] = (int4v){0, 0, 0, 0};

    for (int k0 = 0; k0 < KDIM; k0 += 128) {
#pragma unroll
        for (int it = 0; it < 4; ++it) {
            const int idx = it * 256 + tid;
            const int r = idx >> 3;
            const int cs = ((idx & 7) ^ (r & 7)) << 4;  // swizzled global column
            async_cp16(Ag + (size_t)r * KDIM + k0 + cs, sA + idx * 16);
        }
#pragma unroll
        for (int it = 0; it < 4; ++it) {
            const int idx = it * 256 + tid;
            const int r = idx >> 3;
            const int cs = ((idx & 7) ^ (r & 7)) << 4;
            async_cp16(Bg + (size_t)r * KDIM + k0 + cs, sB + idx * 16);
        }
        __builtin_amdgcn_s_waitcnt(0);
        __syncthreads();

#pragma unroll
        for (int kk = 0; kk < 128; kk += 64) {
            const int coff = (((kk >> 4) + kq) ^ swz) << 4;  // swizzled LDS chunk
            int4v a[4], b[4];
#pragma unroll
            for (int mi = 0; mi < 4; ++mi)
                a[mi] = *(const int4v*)(sA + (wm + mi * 16 + lr) * 128 + coff);
#pragma unroll
            for (int ni = 0; ni < 4; ++ni)
                b[ni] = *(const int4v*)(sB + (wn + ni * 16 + lr) * 128 + coff);
#pragma unroll
            for (int mi = 0; mi < 4; ++mi)
#pragma unroll
                for (int ni = 0; ni < 4; ++ni)
                    acc[mi][ni] = __builtin_amdgcn_mfma_i32_16x16x64_i8(
                        a[mi], b[ni], acc[mi][ni], 0, 0, 0);
        }
        __syncthreads();
    }

    // epilogue: out[t,o] = st*so*( dot - zp_t*Wsum_o - z_o*(Qsum_t - 4096*zp_t) )
#pragma unroll
    for (int mi = 0; mi < 4; ++mi) {
        const int tb = t0 + wm + mi * 16 + ((lane >> 4) << 2);
        float st4[4], zp4[4], qs4[4];
        int zi4[4];
#pragma unroll
        for (int r = 0; r < 4; ++r) {
            st4[r] = sc[tb + r];
            zp4[r] = zpv[tb + r];
            zi4[r] = (int)zp4[r];
            qs4[r] = (float)qsum[tb + r];
        }
#pragma unroll
        for (int ni = 0; ni < 4; ++ni) {
            const int o = o0 + wn + ni * 16 + lr;
            const float so = scales[o];
            const float zo = zeros[o];
            const long long wso = (long long)wsum[o];
#pragma unroll
            for (int r = 0; r < 4; ++r) {
                long long iv = (long long)acc[mi][ni][r] - (long long)zi4[r] * wso;
                float val = (float)iv - zo * (qs4[r] - 4096.0f * zp4[r]);
                out[(size_t)(tb + r) * OUTF + o] = st4[r] * so * val;
            }
        }
    }
}

// ---------------- launch ----------------
extern "C" void kernel_launch(void* const* d_in, const int* in_sizes, int n_in,
                              void* d_out, int out_size, void* d_ws, size_t ws_size,
                              hipStream_t stream) {
    const float* x      = (const float*)d_in[0];
    const int*   w      = (const int*)d_in[1];
    const float* scales = (const float*)d_in[2];
    const float* zeros  = (const float*)d_in[3];
    float* out = (float*)d_out;

    char* ws = (char*)d_ws;
    char*  q8   = ws;                              // 33554432 B
    char*  w8   = ws + 33554432;                   // 45088768 B
    float* sc   = (float*)(ws + 78643200);
    float* zp   = (float*)(ws + 78675968);
    int*   qsum = (int*)(ws + 78708736);
    int*   wsum = (int*)(ws + 78741504);

    quant_x_kernel<<<TOKENS, 256, 0, stream>>>(x, q8, sc, zp, qsum);
    pack_w_kernel<<<OUTF, 256, 0, stream>>>(w, w8, wsum);
    dim3 grid(OUTF / 128, TOKENS / 128);  // (86, 64)
    gemm_i8_kernel<<<grid, 256, 0, stream>>>(q8, w8, sc, zp, qsum, scales, zeros, wsum, out);
}